// Round 15
// baseline (144.094 us; speedup 1.0000x reference)
//
#include <hip/hip_runtime.h>
#include <hip/hip_fp16.h>

// NGP hash-grid encode + fused MLP (16->64->32->2, leaky_relu 0.01)
// N=524288 points, L=8 levels, T=65536 table entries, F=2 features.
// Outputs (concat flat): sigma_clipped[N], alpha_scaled[N], zeros[N].
//
// R15: 2 points/thread re-tried. R11's version failed via VGPR-driven
// occupancy loss; now LDS (34.8KB/block) pins 4 blocks/CU regardless,
// so doubling per-thread loads-in-flight is free occupancy-wise. Issue
// p0+p1's 16 dwordx4 gathers, then consume p0 (blend + MFMA MLP,
// ~2.5K cyc -- covers p1's L2/L3 misses), then consume p1. Everything
// else (int8 supertable builder, f16 MFMA MLP, R12/R13-verified)
// unchanged.

#define NPTS 524288
#define TTAB 65536
#define PI2 2654435761u
#define PI3 805459861u
#define MASK16 65535u
#define C2 31153u   /* PI2 & 0xFFFF */
#define C3 22421u   /* PI3 & 0xFFFF */

typedef float vf2 __attribute__((ext_vector_type(2)));
typedef float vf4 __attribute__((ext_vector_type(4)));
typedef float f32x4 __attribute__((ext_vector_type(4)));
typedef _Float16 half4 __attribute__((ext_vector_type(4)));
typedef _Float16 half8 __attribute__((ext_vector_type(8)));

__device__ __forceinline__ vf4 load16_a8(const float* p) {
    vf4 r; __builtin_memcpy(&r, p, 16); return r;
}
__device__ __forceinline__ float leaky(float v) {
    return fmaf(0.01f, fminf(v, 0.f), fmaxf(v, 0.f));
}
__device__ __forceinline__ unsigned q8(float v) {
    return (unsigned)(int)rintf(v * 25500.f) & 255u;
}

// ---- Pass A: fp32 grid -> int8 grid (1MB) + MFMA weight-frag pack ----
__global__ __launch_bounds__(256) void convert_i8_pack(
    const float* __restrict__ g, ushort* __restrict__ G8,
    const float* __restrict__ w0, const float* __restrict__ w1,
    _Float16* __restrict__ b0f, _Float16* __restrict__ b1f)
{
    const int i = blockIdx.x * 256 + threadIdx.x;   // 65536 threads, 8 entries each
    const float4* __restrict__ gp = (const float4*)g + (size_t)i * 4;
    float4 v0 = gp[0], v1 = gp[1], v2 = gp[2], v3 = gp[3];
    uint4 o;
    o.x = q8(v0.x) | (q8(v0.y) << 8) | (q8(v0.z) << 16) | (q8(v0.w) << 24);
    o.y = q8(v1.x) | (q8(v1.y) << 8) | (q8(v1.z) << 16) | (q8(v1.w) << 24);
    o.z = q8(v2.x) | (q8(v2.y) << 8) | (q8(v2.z) << 16) | (q8(v2.w) << 24);
    o.w = q8(v3.x) | (q8(v3.y) << 8) | (q8(v3.z) << 16) | (q8(v3.w) << 24);
    ((uint4*)G8)[i] = o;

    if (blockIdx.x == 0 && threadIdx.x < 64) {
        const int L = threadIdx.x;
        const int quad = L >> 4, m = L & 15;
        #pragma unroll
        for (int nt = 0; nt < 4; ++nt)
            #pragma unroll
            for (int j = 0; j < 4; ++j)
                b0f[(nt * 64 + L) * 4 + j] =
                    (_Float16)w0[(4 * quad + j) * 64 + nt * 16 + m];
        #pragma unroll
        for (int ks = 0; ks < 4; ++ks)
            #pragma unroll
            for (int nt = 0; nt < 2; ++nt)
                #pragma unroll
                for (int j = 0; j < 4; ++j)
                    b1f[((ks * 2 + nt) * 64 + L) * 4 + j] =
                        (_Float16)w1[(ks * 16 + 4 * quad + j) * 32 + nt * 16 + m];
    }
}

// ---- Pass B: int8 supertable (8MB) from int8 grid (R13-verified) ----
__global__ __launch_bounds__(256) void build_supertable_v2(
    const ushort* __restrict__ G8, uint4* __restrict__ V)
{
    const unsigned t = blockIdx.x * 256 + threadIdx.x;  // 131072 threads
    const unsigned l = t >> 14;
    const unsigned r = (t & 16383u) * 4u;
    const ushort* __restrict__ gl = G8 + l * TTAB;

    const unsigned offs[4] = {0u, C2, C3, C2 + C3};
    unsigned dws[4][4];   // [s][d]
    #pragma unroll
    for (int s = 0; s < 4; ++s) {
        const unsigned st = (r + offs[s]) & MASK16;
        if (st <= TTAB - 5u) {
            const char* bp = (const char*)gl + ((2u * st) & ~7u);
            uint4 W; __builtin_memcpy(&W, bp, 16);
            const unsigned off8 = ((2u * st) & 7u) * 8u;
            unsigned long long Lq =
                (unsigned long long)W.x | ((unsigned long long)W.y << 32);
            unsigned long long Hq =
                (unsigned long long)W.z | ((unsigned long long)W.w << 32);
            unsigned long long X =
                off8 ? ((Lq >> off8) | (Hq << (64u - off8))) : Lq;
            unsigned long long Yt = Hq >> off8;
            dws[s][0] = (unsigned)X;
            dws[s][1] = (unsigned)(X >> 16);
            dws[s][2] = (unsigned)(X >> 32);
            dws[s][3] = (unsigned)((X >> 48) & 0xFFFFull)
                      | (((unsigned)Yt & 0xFFFFu) << 16);
        } else {
            unsigned short us[5];
            #pragma unroll
            for (int d = 0; d < 5; ++d) us[d] = gl[(st + d) & MASK16];
            #pragma unroll
            for (int d = 0; d < 4; ++d)
                dws[s][d] = (unsigned)us[d] | ((unsigned)us[d + 1] << 16);
        }
    }
    uint4* dst = V + ((size_t)l * TTAB + r);
    #pragma unroll
    for (int d = 0; d < 4; ++d)
        dst[d] = (uint4){dws[0][d], dws[1][d], dws[2][d], dws[3][d]};
}

// ---- device helpers ----
__device__ __forceinline__ void hash_point(
    float px, float py, float pz,
    float* fxs, float* fys, float* fzs, unsigned* hb)
{
    const float levels[8] = {2.0f, 2.6946f, 3.6301f, 4.8907f,
                             6.5893f, 8.8766f, 11.959f, 16.111f};
    #pragma unroll
    for (int l = 0; l < 8; ++l) {
        const float lev = levels[l];
        float xs0 = px * lev, xs1 = py * lev, xs2 = pz * lev;
        float fl0 = floorf(xs0), fl1 = floorf(xs1), fl2 = floorf(xs2);
        fxs[l] = xs0 - fl0;
        fys[l] = xs1 - fl1;
        fzs[l] = xs2 - fl2;
        unsigned cx = (unsigned)(int)fl0;
        unsigned cy = (unsigned)(int)fl1;
        unsigned cz = (unsigned)(int)fl2;
        hb[l] = cx + cy * PI2 + cz * PI3;   // uint32 wrap = ref semantics
    }
}

__device__ __forceinline__ vf2 blend_voxel(
    uint4 praw, float fx, float fy, float fz)
{
    const float gx = 1.f - fx, gy = 1.f - fy, gz = 1.f - fz;
    const float wyz[4] = {gy * gz, fy * gz, gy * fz, fy * fz};
    unsigned q[4] = {praw.x, praw.y, praw.z, praw.w};
    vf2 e = {0.f, 0.f};
    #pragma unroll
    for (int s = 0; s < 4; ++s) {
        float u0 = (float)(q[s] & 0xFFu);
        float u1 = (float)((q[s] >> 8) & 0xFFu);
        float u2 = (float)((q[s] >> 16) & 0xFFu);
        float u3 = (float)(q[s] >> 24);
        vf2 lo = {u0, u1}, hi = {u2, u3};
        const float wl = gx * wyz[s], wr = fx * wyz[s];
        e = __builtin_elementwise_fma((vf2){wl, wl}, lo, e);
        e = __builtin_elementwise_fma((vf2){wr, wr}, hi, e);
    }
    return e;
}

// MFMA MLP + epilogue for one wave-batch of 64 points (enc2 per lane).
__device__ __forceinline__ void mlp_and_store(
    char* ws, const vf2* enc2, int lane, int quad, int m16,
    const float* __restrict__ b0,
    const float* __restrict__ b1,
    const float* __restrict__ w2,
    const float* __restrict__ b2,
    const _Float16* __restrict__ b0f,
    const _Float16* __restrict__ b1f,
    float* __restrict__ out, int n)
{
    // ENC -> LDS as f16, [pt][24] halves.
    _Float16* encl = (_Float16*)ws;
    half8 e0, e1;
    #pragma unroll
    for (int l = 0; l < 4; ++l) {
        e0[2 * l + 0] = (_Float16)enc2[l].x;
        e0[2 * l + 1] = (_Float16)enc2[l].y;
        e1[2 * l + 0] = (_Float16)enc2[l + 4].x;
        e1[2 * l + 1] = (_Float16)enc2[l + 4].y;
    }
    *(half8*)(encl + lane * 24) = e0;
    *(half8*)(encl + lane * 24 + 8) = e1;

    // Layer 0: h0[64x64] = enc[64x16] * w0[16x64].
    half4 a0[4];
    #pragma unroll
    for (int mt = 0; mt < 4; ++mt)
        a0[mt] = *(const half4*)(encl + (mt * 16 + m16) * 24 + 4 * quad);

    _Float16* h0l = (_Float16*)ws;   // [pt][68] halves
    #pragma unroll
    for (int nt = 0; nt < 4; ++nt) {
        half4 bf = *(const half4*)(b0f + (nt * 64 + lane) * 4);
        float bias = b0[nt * 16 + m16];
        f32x4 c[4];
        #pragma unroll
        for (int mt = 0; mt < 4; ++mt)
            c[mt] = __builtin_amdgcn_mfma_f32_16x16x16f16(
                a0[mt], bf, (f32x4){0.f, 0.f, 0.f, 0.f}, 0, 0, 0);
        #pragma unroll
        for (int mt = 0; mt < 4; ++mt)
            #pragma unroll
            for (int r = 0; r < 4; ++r) {
                float v = leaky(c[mt][r] + bias);
                h0l[(mt * 16 + quad * 4 + r) * 68 + nt * 16 + m16] =
                    (_Float16)v;
            }
    }

    // Layer 1: h1[64x32] = h0[64x64] * w1[64x32].
    half4 a1[4][4];
    #pragma unroll
    for (int ks = 0; ks < 4; ++ks)
        #pragma unroll
        for (int mt = 0; mt < 4; ++mt)
            a1[ks][mt] = *(const half4*)(h0l + (mt * 16 + m16) * 68
                                         + ks * 16 + 4 * quad);

    float* h1l = (float*)ws;   // [pt][33] f32
    #pragma unroll
    for (int nt = 0; nt < 2; ++nt) {
        f32x4 c[4];
        #pragma unroll
        for (int mt = 0; mt < 4; ++mt) c[mt] = (f32x4){0.f, 0.f, 0.f, 0.f};
        #pragma unroll
        for (int ks = 0; ks < 4; ++ks) {
            half4 bf = *(const half4*)(b1f + ((ks * 2 + nt) * 64 + lane) * 4);
            #pragma unroll
            for (int mt = 0; mt < 4; ++mt)
                c[mt] = __builtin_amdgcn_mfma_f32_16x16x16f16(
                    a1[ks][mt], bf, c[mt], 0, 0, 0);
        }
        float bias = b1[nt * 16 + m16];
        #pragma unroll
        for (int mt = 0; mt < 4; ++mt)
            #pragma unroll
            for (int r = 0; r < 4; ++r)
                h1l[(mt * 16 + quad * 4 + r) * 33 + nt * 16 + m16] =
                    leaky(c[mt][r] + bias);
    }

    // Layer 2: 32 -> 2 per thread.
    const float* hrow = h1l + lane * 33;
    float s0 = b2[0], s1 = b2[1];
    #pragma unroll
    for (int k = 0; k < 32; ++k) {
        float hk = hrow[k];
        s0 = fmaf(hk, w2[k * 2 + 0], s0);
        s1 = fmaf(hk, w2[k * 2 + 1], s1);
    }

    __builtin_nontemporal_store((s0 > -1.0f) ? s0 : 0.0f, &out[n]);
    __builtin_nontemporal_store(fminf(0.0f, s1) * 0.1f, &out[NPTS + n]);
    __builtin_nontemporal_store(0.0f, &out[2 * NPTS + n]);
}

// ---- Main kernel: 2 points/thread, gathers pipelined under p0's MLP ----
#define WSB 8704   /* per-wave LDS scratch bytes */

__global__ __launch_bounds__(256, 4) void ngp_mfma2(
    const float* __restrict__ x,
    const float* __restrict__ b0,
    const float* __restrict__ b1,
    const float* __restrict__ w2,
    const float* __restrict__ b2,
    float* __restrict__ out,
    const uint4* __restrict__ V,
    const _Float16* __restrict__ b0f,
    const _Float16* __restrict__ b1f)
{
    __shared__ __align__(16) char smem[4 * WSB];
    const int lane = threadIdx.x & 63;
    const int wave = threadIdx.x >> 6;
    const int quad = lane >> 4, m16 = lane & 15;
    char* ws = smem + wave * WSB;

    const int n0 = blockIdx.x * 512 + threadIdx.x;
    const int n1 = n0 + 256;

    const float px0 = __builtin_nontemporal_load(&x[n0 * 3 + 0]);
    const float py0 = __builtin_nontemporal_load(&x[n0 * 3 + 1]);
    const float pz0 = __builtin_nontemporal_load(&x[n0 * 3 + 2]);
    const float px1 = __builtin_nontemporal_load(&x[n1 * 3 + 0]);
    const float py1 = __builtin_nontemporal_load(&x[n1 * 3 + 1]);
    const float pz1 = __builtin_nontemporal_load(&x[n1 * 3 + 2]);

    float fxs0[8], fys0[8], fzs0[8]; unsigned hb0[8];
    float fxs1[8], fys1[8], fzs1[8]; unsigned hb1[8];
    hash_point(px0, py0, pz0, fxs0, fys0, fzs0, hb0);
    hash_point(px1, py1, pz1, fxs1, fys1, fzs1, hb1);

    // Issue all 16 gathers (8 per point) back-to-back.
    uint4 praw0[8], praw1[8];
    #pragma unroll
    for (int l = 0; l < 8; ++l)
        praw0[l] = V[(size_t)l * TTAB + (int)(hb0[l] & MASK16)];
    #pragma unroll
    for (int l = 0; l < 8; ++l)
        praw1[l] = V[(size_t)l * TTAB + (int)(hb1[l] & MASK16)];
    __builtin_amdgcn_sched_barrier(0);

    const float S = 1.0f / 25500.0f;

    // Consume p0 (waits vmcnt(8): p1's loads stay in flight through the
    // whole p0 blend+MLP -- their miss latency is hidden here).
    vf2 enc2[8];
    #pragma unroll
    for (int l = 0; l < 8; ++l)
        enc2[l] = blend_voxel(praw0[l], fxs0[l], fys0[l], fzs0[l])
                  * (vf2){S, S};
    mlp_and_store(ws, enc2, lane, quad, m16, b0, b1, w2, b2, b0f, b1f,
                  out, n0);

    __builtin_amdgcn_sched_barrier(0);

    // Consume p1.
    #pragma unroll
    for (int l = 0; l < 8; ++l)
        enc2[l] = blend_voxel(praw1[l], fxs1[l], fys1[l], fzs1[l])
                  * (vf2){S, S};
    mlp_and_store(ws, enc2, lane, quad, m16, b0, b1, w2, b2, b0f, b1f,
                  out, n1);
}

// ---- Fallback (ws too small): R6-style fp32 paired gathers + VALU MLP ----
__global__ __launch_bounds__(256) void ngp_fallback(
    const float* __restrict__ x,
    const float* __restrict__ gridp,
    const float* __restrict__ w0,
    const float* __restrict__ b0p,
    const float* __restrict__ w1,
    const float* __restrict__ b1,
    const float* __restrict__ w2,
    const float* __restrict__ b2,
    float* __restrict__ out)
{
    const int n = blockIdx.x * 256 + threadIdx.x;
    const float px = x[n * 3 + 0], py = x[n * 3 + 1], pz = x[n * 3 + 2];
    float fxs[8], fys[8], fzs[8]; unsigned hb[8];
    hash_point(px, py, pz, fxs, fys, fzs, hb);

    vf2 enc2[8];
    #pragma unroll
    for (int l = 0; l < 8; ++l) {
        const float fx = fxs[l], fy = fys[l], fz = fzs[l];
        const float gx = 1.f - fx, gy = 1.f - fy, gz = 1.f - fz;
        const vf2 first = {gridp[l * TTAB * 2 + 0], gridp[l * TTAB * 2 + 1]};
        vf2 e = {0.f, 0.f};
        #pragma unroll
        for (int p = 0; p < 4; ++p) {
            const unsigned delta = ((p >> 1) ? PI2 : 0u) + ((p & 1) ? PI3 : 0u);
            unsigned b = (hb[l] + delta) & MASK16;
            const bool wrap = (b == MASK16);
            unsigned lidx = b - (wrap ? 1u : 0u);
            vf4 pr = load16_a8(gridp + ((unsigned)(l * TTAB) + lidx) * 2u);
            vf2 lo = {pr.x, pr.y}, hi = {pr.z, pr.w};
            vf2 c0 = wrap ? hi : lo;
            vf2 c1 = wrap ? first : hi;
            const float wyz = ((p >> 1) ? fy : gy) * ((p & 1) ? fz : gz);
            const float wl = gx * wyz, wr = fx * wyz;
            e = __builtin_elementwise_fma((vf2){wl, wl}, c0, e);
            e = __builtin_elementwise_fma((vf2){wr, wr}, c1, e);
        }
        enc2[l] = e;
    }

    vf2 h1p[16];
    #pragma unroll
    for (int m = 0; m < 16; ++m) h1p[m] = (vf2){0.f, 0.f};
    #pragma unroll 2
    for (int j = 0; j < 64; ++j) {
        vf2 acc = {b0p[j], 0.f};
        #pragma unroll
        for (int m = 0; m < 8; ++m) {
            vf2 wv = {w0[(2 * m) * 64 + j], w0[(2 * m + 1) * 64 + j]};
            acc = __builtin_elementwise_fma(enc2[m], wv, acc);
        }
        float a = acc.x + acc.y;
        a = leaky(a);
        vf2 av = {a, a};
        const vf2* __restrict__ w1j = (const vf2*)&w1[j * 32];
        #pragma unroll
        for (int m = 0; m < 16; ++m)
            h1p[m] = __builtin_elementwise_fma(av, w1j[m], h1p[m]);
    }
    const vf2* __restrict__ b1p = (const vf2*)b1;
    float s0 = b2[0], s1 = b2[1];
    #pragma unroll
    for (int m = 0; m < 16; ++m) {
        vf2 hk = h1p[m] + b1p[m];
        float h0 = leaky(hk.x), h1v = leaky(hk.y);
        s0 = fmaf(h0, w2[(2 * m) * 2 + 0], s0);
        s1 = fmaf(h0, w2[(2 * m) * 2 + 1], s1);
        s0 = fmaf(h1v, w2[(2 * m + 1) * 2 + 0], s0);
        s1 = fmaf(h1v, w2[(2 * m + 1) * 2 + 1], s1);
    }
    out[n] = (s0 > -1.0f) ? s0 : 0.0f;
    out[NPTS + n] = fminf(0.0f, s1) * 0.1f;
    out[2 * NPTS + n] = 0.0f;
}

extern "C" void kernel_launch(void* const* d_in, const int* in_sizes, int n_in,
                              void* d_out, int out_size, void* d_ws, size_t ws_size,
                              hipStream_t stream) {
    const float* x    = (const float*)d_in[0];
    const float* grid = (const float*)d_in[1];
    const float* w0   = (const float*)d_in[2];
    const float* b0   = (const float*)d_in[3];
    const float* w1   = (const float*)d_in[4];
    const float* b1   = (const float*)d_in[5];
    const float* w2   = (const float*)d_in[6];
    const float* b2   = (const float*)d_in[7];
    float* out = (float*)d_out;

    const size_t vt_bytes  = (size_t)8 * TTAB * 16;          // 8 MB supertable
    const size_t b0f_bytes = 4 * 64 * 4 * sizeof(_Float16);  // 2 KB
    const size_t b1f_bytes = 8 * 64 * 4 * sizeof(_Float16);  // 4 KB
    const size_t g8_bytes  = (size_t)8 * TTAB * 2;           // 1 MB int8 grid
    if (ws_size >= vt_bytes + b0f_bytes + b1f_bytes + g8_bytes) {
        uint4* V = (uint4*)d_ws;
        _Float16* b0f = (_Float16*)((char*)d_ws + vt_bytes);
        _Float16* b1f = (_Float16*)((char*)d_ws + vt_bytes + b0f_bytes);
        ushort* G8 = (ushort*)((char*)d_ws + vt_bytes + b0f_bytes + b1f_bytes);
        convert_i8_pack<<<256, 256, 0, stream>>>(grid, G8, w0, w1, b0f, b1f);
        build_supertable_v2<<<512, 256, 0, stream>>>(G8, V);
        ngp_mfma2<<<NPTS / 512, 256, 0, stream>>>(
            x, b0, b1, w2, b2, out, V, b0f, b1f);
    } else {
        ngp_fallback<<<NPTS / 256, 256, 0, stream>>>(
            x, grid, w0, b0, w1, b1, w2, b2, out);
    }
}

// Round 16
// 120.840 us; speedup vs baseline: 1.1924x; 1.1924x over previous
//
#include <hip/hip_runtime.h>
#include <hip/hip_fp16.h>

// NGP hash-grid encode + fused MLP (16->64->32->2, leaky_relu 0.01)
// N=524288 points, L=8 levels, T=65536 table entries, F=2 features.
// Outputs (concat flat): sigma_clipped[N], alpha_scaled[N], zeros[N].
//
// R16 = revert to R14 (best verified: bench 120.9us, main 45.5us).
// R15's 2-point pipeline spilled (WRITE_SIZE 6->54MB scratch) and
// regressed; R11/R14/R15 together establish that the gather phase's
// two cost terms -- request slots (~23us, 8 divergent dwordx4/thread
// at ~0.3 lane-req/cyc/CU) and L2-miss fill (~20us, 8MB table vs
// 4MB/XCD L2) -- are additive and not removable by restructuring at
// this workload shape. MLP rides the idle MFMA pipe (f16, m89-verified
// layouts); builder passes are request-optimized; absmax 3.05e-5.

#define NPTS 524288
#define TTAB 65536
#define PI2 2654435761u
#define PI3 805459861u
#define MASK16 65535u
#define C2 31153u   /* PI2 & 0xFFFF */
#define C3 22421u   /* PI3 & 0xFFFF */

typedef float vf2 __attribute__((ext_vector_type(2)));
typedef float vf4 __attribute__((ext_vector_type(4)));
typedef float f32x4 __attribute__((ext_vector_type(4)));
typedef _Float16 half4 __attribute__((ext_vector_type(4)));
typedef _Float16 half8 __attribute__((ext_vector_type(8)));

__device__ __forceinline__ vf4 load16_a8(const float* p) {
    vf4 r; __builtin_memcpy(&r, p, 16); return r;
}
__device__ __forceinline__ float leaky(float v) {
    return fmaf(0.01f, fminf(v, 0.f), fmaxf(v, 0.f));
}
__device__ __forceinline__ unsigned q8(float v) {
    return (unsigned)(int)rintf(v * 25500.f) & 255u;
}

// ---- Pass A: fp32 grid -> int8 grid (1MB) + MFMA weight-frag pack ----
__global__ __launch_bounds__(256) void convert_i8_pack(
    const float* __restrict__ g, ushort* __restrict__ G8,
    const float* __restrict__ w0, const float* __restrict__ w1,
    _Float16* __restrict__ b0f, _Float16* __restrict__ b1f)
{
    const int i = blockIdx.x * 256 + threadIdx.x;   // 65536 threads, 8 entries each
    const float4* __restrict__ gp = (const float4*)g + (size_t)i * 4;
    float4 v0 = gp[0], v1 = gp[1], v2 = gp[2], v3 = gp[3];
    uint4 o;
    o.x = q8(v0.x) | (q8(v0.y) << 8) | (q8(v0.z) << 16) | (q8(v0.w) << 24);
    o.y = q8(v1.x) | (q8(v1.y) << 8) | (q8(v1.z) << 16) | (q8(v1.w) << 24);
    o.z = q8(v2.x) | (q8(v2.y) << 8) | (q8(v2.z) << 16) | (q8(v2.w) << 24);
    o.w = q8(v3.x) | (q8(v3.y) << 8) | (q8(v3.z) << 16) | (q8(v3.w) << 24);
    ((uint4*)G8)[i] = o;

    if (blockIdx.x == 0 && threadIdx.x < 64) {
        const int L = threadIdx.x;
        const int quad = L >> 4, m = L & 15;
        #pragma unroll
        for (int nt = 0; nt < 4; ++nt)
            #pragma unroll
            for (int j = 0; j < 4; ++j)
                b0f[(nt * 64 + L) * 4 + j] =
                    (_Float16)w0[(4 * quad + j) * 64 + nt * 16 + m];
        #pragma unroll
        for (int ks = 0; ks < 4; ++ks)
            #pragma unroll
            for (int nt = 0; nt < 2; ++nt)
                #pragma unroll
                for (int j = 0; j < 4; ++j)
                    b1f[((ks * 2 + nt) * 64 + L) * 4 + j] =
                        (_Float16)w1[(ks * 16 + 4 * quad + j) * 32 + nt * 16 + m];
    }
}

// ---- Pass B: int8 supertable (8MB) from int8 grid (R13-verified) ----
__global__ __launch_bounds__(256) void build_supertable_v2(
    const ushort* __restrict__ G8, uint4* __restrict__ V)
{
    const unsigned t = blockIdx.x * 256 + threadIdx.x;  // 131072 threads
    const unsigned l = t >> 14;
    const unsigned r = (t & 16383u) * 4u;
    const ushort* __restrict__ gl = G8 + l * TTAB;

    const unsigned offs[4] = {0u, C2, C3, C2 + C3};
    unsigned dws[4][4];   // [s][d]
    #pragma unroll
    for (int s = 0; s < 4; ++s) {
        const unsigned st = (r + offs[s]) & MASK16;
        if (st <= TTAB - 5u) {
            const char* bp = (const char*)gl + ((2u * st) & ~7u);
            uint4 W; __builtin_memcpy(&W, bp, 16);
            const unsigned off8 = ((2u * st) & 7u) * 8u;
            unsigned long long Lq =
                (unsigned long long)W.x | ((unsigned long long)W.y << 32);
            unsigned long long Hq =
                (unsigned long long)W.z | ((unsigned long long)W.w << 32);
            unsigned long long X =
                off8 ? ((Lq >> off8) | (Hq << (64u - off8))) : Lq;
            unsigned long long Yt = Hq >> off8;
            dws[s][0] = (unsigned)X;
            dws[s][1] = (unsigned)(X >> 16);
            dws[s][2] = (unsigned)(X >> 32);
            dws[s][3] = (unsigned)((X >> 48) & 0xFFFFull)
                      | (((unsigned)Yt & 0xFFFFu) << 16);
        } else {
            unsigned short us[5];
            #pragma unroll
            for (int d = 0; d < 5; ++d) us[d] = gl[(st + d) & MASK16];
            #pragma unroll
            for (int d = 0; d < 4; ++d)
                dws[s][d] = (unsigned)us[d] | ((unsigned)us[d + 1] << 16);
        }
    }
    uint4* dst = V + ((size_t)l * TTAB + r);
    #pragma unroll
    for (int d = 0; d < 4; ++d)
        dst[d] = (uint4){dws[0][d], dws[1][d], dws[2][d], dws[3][d]};
}

// ---- device helper: hash + fractions ----
__device__ __forceinline__ void hash_point(
    float px, float py, float pz,
    float* fxs, float* fys, float* fzs, unsigned* hb)
{
    const float levels[8] = {2.0f, 2.6946f, 3.6301f, 4.8907f,
                             6.5893f, 8.8766f, 11.959f, 16.111f};
    #pragma unroll
    for (int l = 0; l < 8; ++l) {
        const float lev = levels[l];
        float xs0 = px * lev, xs1 = py * lev, xs2 = pz * lev;
        float fl0 = floorf(xs0), fl1 = floorf(xs1), fl2 = floorf(xs2);
        fxs[l] = xs0 - fl0;
        fys[l] = xs1 - fl1;
        fzs[l] = xs2 - fl2;
        unsigned cx = (unsigned)(int)fl0;
        unsigned cy = (unsigned)(int)fl1;
        unsigned cz = (unsigned)(int)fl2;
        hb[l] = cx + cy * PI2 + cz * PI3;   // uint32 wrap = ref semantics
    }
}

// Dequant + trilinear blend of one level's packed voxel.
__device__ __forceinline__ vf2 blend_voxel(
    uint4 praw, float fx, float fy, float fz)
{
    const float gx = 1.f - fx, gy = 1.f - fy, gz = 1.f - fz;
    const float wyz[4] = {gy * gz, fy * gz, gy * fz, fy * fz};
    unsigned q[4] = {praw.x, praw.y, praw.z, praw.w};
    vf2 e = {0.f, 0.f};
    #pragma unroll
    for (int s = 0; s < 4; ++s) {
        float u0 = (float)(q[s] & 0xFFu);
        float u1 = (float)((q[s] >> 8) & 0xFFu);
        float u2 = (float)((q[s] >> 16) & 0xFFu);
        float u3 = (float)(q[s] >> 24);
        vf2 lo = {u0, u1}, hi = {u2, u3};
        const float wl = gx * wyz[s], wr = fx * wyz[s];
        e = __builtin_elementwise_fma((vf2){wl, wl}, lo, e);
        e = __builtin_elementwise_fma((vf2){wr, wr}, hi, e);
    }
    return e;
}

// ---- Main kernel: phased gathers + MFMA MLP ----
#define WSB 8704   /* per-wave LDS scratch bytes */

__global__ __launch_bounds__(256, 4) void ngp_mfma(
    const float* __restrict__ x,
    const float* __restrict__ b0,
    const float* __restrict__ b1,
    const float* __restrict__ w2,
    const float* __restrict__ b2,
    float* __restrict__ out,
    const uint4* __restrict__ V,
    const _Float16* __restrict__ b0f,
    const _Float16* __restrict__ b1f)
{
    __shared__ __align__(16) char smem[4 * WSB];
    const int lane = threadIdx.x & 63;
    const int wave = threadIdx.x >> 6;
    const int quad = lane >> 4, m16 = lane & 15;
    char* ws = smem + wave * WSB;

    const int n = blockIdx.x * 256 + threadIdx.x;
    const float px = __builtin_nontemporal_load(&x[n * 3 + 0]);
    const float py = __builtin_nontemporal_load(&x[n * 3 + 1]);
    const float pz = __builtin_nontemporal_load(&x[n * 3 + 2]);

    float fxs[8], fys[8], fzs[8]; unsigned hb[8];
    hash_point(px, py, pz, fxs, fys, fzs, hb);

    vf2 enc2[8];
    const float S = 1.0f / 25500.0f;

    // Phase 1: levels 0-3.
    {
        uint4 praw[4];
        #pragma unroll
        for (int l = 0; l < 4; ++l)
            praw[l] = V[(size_t)l * TTAB + (int)(hb[l] & MASK16)];
        __builtin_amdgcn_sched_barrier(0);
        #pragma unroll
        for (int l = 0; l < 4; ++l)
            enc2[l] = blend_voxel(praw[l], fxs[l], fys[l], fzs[l])
                      * (vf2){S, S};
    }
    // Phase 2: levels 4-7.
    {
        uint4 praw[4];
        #pragma unroll
        for (int l = 0; l < 4; ++l)
            praw[l] = V[(size_t)(l + 4) * TTAB + (int)(hb[l + 4] & MASK16)];
        __builtin_amdgcn_sched_barrier(0);
        #pragma unroll
        for (int l = 0; l < 4; ++l)
            enc2[l + 4] = blend_voxel(praw[l], fxs[l + 4], fys[l + 4],
                                      fzs[l + 4]) * (vf2){S, S};
    }

    // ENC -> LDS as f16, [pt][24] halves.
    _Float16* encl = (_Float16*)ws;
    half8 e0, e1;
    #pragma unroll
    for (int l = 0; l < 4; ++l) {
        e0[2 * l + 0] = (_Float16)enc2[l].x;
        e0[2 * l + 1] = (_Float16)enc2[l].y;
        e1[2 * l + 0] = (_Float16)enc2[l + 4].x;
        e1[2 * l + 1] = (_Float16)enc2[l + 4].y;
    }
    *(half8*)(encl + lane * 24) = e0;
    *(half8*)(encl + lane * 24 + 8) = e1;

    // Layer 0: h0[64x64] = enc[64x16] * w0[16x64].
    half4 a0[4];
    #pragma unroll
    for (int mt = 0; mt < 4; ++mt)
        a0[mt] = *(const half4*)(encl + (mt * 16 + m16) * 24 + 4 * quad);

    _Float16* h0l = (_Float16*)ws;   // [pt][68] halves
    #pragma unroll
    for (int nt = 0; nt < 4; ++nt) {
        half4 bf = *(const half4*)(b0f + (nt * 64 + lane) * 4);
        float bias = b0[nt * 16 + m16];
        f32x4 c[4];
        #pragma unroll
        for (int mt = 0; mt < 4; ++mt)
            c[mt] = __builtin_amdgcn_mfma_f32_16x16x16f16(
                a0[mt], bf, (f32x4){0.f, 0.f, 0.f, 0.f}, 0, 0, 0);
        #pragma unroll
        for (int mt = 0; mt < 4; ++mt)
            #pragma unroll
            for (int r = 0; r < 4; ++r) {
                float v = leaky(c[mt][r] + bias);
                h0l[(mt * 16 + quad * 4 + r) * 68 + nt * 16 + m16] =
                    (_Float16)v;
            }
    }

    // Layer 1: h1[64x32] = h0[64x64] * w1[64x32].
    half4 a1[4][4];
    #pragma unroll
    for (int ks = 0; ks < 4; ++ks)
        #pragma unroll
        for (int mt = 0; mt < 4; ++mt)
            a1[ks][mt] = *(const half4*)(h0l + (mt * 16 + m16) * 68
                                         + ks * 16 + 4 * quad);

    float* h1l = (float*)ws;   // [pt][33] f32
    #pragma unroll
    for (int nt = 0; nt < 2; ++nt) {
        f32x4 c[4];
        #pragma unroll
        for (int mt = 0; mt < 4; ++mt) c[mt] = (f32x4){0.f, 0.f, 0.f, 0.f};
        #pragma unroll
        for (int ks = 0; ks < 4; ++ks) {
            half4 bf = *(const half4*)(b1f + ((ks * 2 + nt) * 64 + lane) * 4);
            #pragma unroll
            for (int mt = 0; mt < 4; ++mt)
                c[mt] = __builtin_amdgcn_mfma_f32_16x16x16f16(
                    a1[ks][mt], bf, c[mt], 0, 0, 0);
        }
        float bias = b1[nt * 16 + m16];
        #pragma unroll
        for (int mt = 0; mt < 4; ++mt)
            #pragma unroll
            for (int r = 0; r < 4; ++r)
                h1l[(mt * 16 + quad * 4 + r) * 33 + nt * 16 + m16] =
                    leaky(c[mt][r] + bias);
    }

    // Layer 2: 32 -> 2 per thread.
    const float* hrow = h1l + lane * 33;
    float s0 = b2[0], s1 = b2[1];
    #pragma unroll
    for (int k = 0; k < 32; ++k) {
        float hk = hrow[k];
        s0 = fmaf(hk, w2[k * 2 + 0], s0);
        s1 = fmaf(hk, w2[k * 2 + 1], s1);
    }

    __builtin_nontemporal_store((s0 > -1.0f) ? s0 : 0.0f, &out[n]);
    __builtin_nontemporal_store(fminf(0.0f, s1) * 0.1f, &out[NPTS + n]);
    __builtin_nontemporal_store(0.0f, &out[2 * NPTS + n]);
}

// ---- Fallback (ws too small): R6-style fp32 paired gathers + VALU MLP ----
__global__ __launch_bounds__(256) void ngp_fallback(
    const float* __restrict__ x,
    const float* __restrict__ gridp,
    const float* __restrict__ w0,
    const float* __restrict__ b0p,
    const float* __restrict__ w1,
    const float* __restrict__ b1,
    const float* __restrict__ w2,
    const float* __restrict__ b2,
    float* __restrict__ out)
{
    const int n = blockIdx.x * 256 + threadIdx.x;
    const float px = x[n * 3 + 0], py = x[n * 3 + 1], pz = x[n * 3 + 2];
    float fxs[8], fys[8], fzs[8]; unsigned hb[8];
    hash_point(px, py, pz, fxs, fys, fzs, hb);

    vf2 enc2[8];
    #pragma unroll
    for (int l = 0; l < 8; ++l) {
        const float fx = fxs[l], fy = fys[l], fz = fzs[l];
        const float gx = 1.f - fx, gy = 1.f - fy, gz = 1.f - fz;
        const vf2 first = {gridp[l * TTAB * 2 + 0], gridp[l * TTAB * 2 + 1]};
        vf2 e = {0.f, 0.f};
        #pragma unroll
        for (int p = 0; p < 4; ++p) {
            const unsigned delta = ((p >> 1) ? PI2 : 0u) + ((p & 1) ? PI3 : 0u);
            unsigned b = (hb[l] + delta) & MASK16;
            const bool wrap = (b == MASK16);
            unsigned lidx = b - (wrap ? 1u : 0u);
            vf4 pr = load16_a8(gridp + ((unsigned)(l * TTAB) + lidx) * 2u);
            vf2 lo = {pr.x, pr.y}, hi = {pr.z, pr.w};
            vf2 c0 = wrap ? hi : lo;
            vf2 c1 = wrap ? first : hi;
            const float wyz = ((p >> 1) ? fy : gy) * ((p & 1) ? fz : gz);
            const float wl = gx * wyz, wr = fx * wyz;
            e = __builtin_elementwise_fma((vf2){wl, wl}, c0, e);
            e = __builtin_elementwise_fma((vf2){wr, wr}, c1, e);
        }
        enc2[l] = e;
    }

    vf2 h1p[16];
    #pragma unroll
    for (int m = 0; m < 16; ++m) h1p[m] = (vf2){0.f, 0.f};
    #pragma unroll 2
    for (int j = 0; j < 64; ++j) {
        vf2 acc = {b0p[j], 0.f};
        #pragma unroll
        for (int m = 0; m < 8; ++m) {
            vf2 wv = {w0[(2 * m) * 64 + j], w0[(2 * m + 1) * 64 + j]};
            acc = __builtin_elementwise_fma(enc2[m], wv, acc);
        }
        float a = acc.x + acc.y;
        a = leaky(a);
        vf2 av = {a, a};
        const vf2* __restrict__ w1j = (const vf2*)&w1[j * 32];
        #pragma unroll
        for (int m = 0; m < 16; ++m)
            h1p[m] = __builtin_elementwise_fma(av, w1j[m], h1p[m]);
    }
    const vf2* __restrict__ b1p = (const vf2*)b1;
    float s0 = b2[0], s1 = b2[1];
    #pragma unroll
    for (int m = 0; m < 16; ++m) {
        vf2 hk = h1p[m] + b1p[m];
        float h0 = leaky(hk.x), h1v = leaky(hk.y);
        s0 = fmaf(h0, w2[(2 * m) * 2 + 0], s0);
        s1 = fmaf(h0, w2[(2 * m) * 2 + 1], s1);
        s0 = fmaf(h1v, w2[(2 * m + 1) * 2 + 0], s0);
        s1 = fmaf(h1v, w2[(2 * m + 1) * 2 + 1], s1);
    }
    out[n] = (s0 > -1.0f) ? s0 : 0.0f;
    out[NPTS + n] = fminf(0.0f, s1) * 0.1f;
    out[2 * NPTS + n] = 0.0f;
}

extern "C" void kernel_launch(void* const* d_in, const int* in_sizes, int n_in,
                              void* d_out, int out_size, void* d_ws, size_t ws_size,
                              hipStream_t stream) {
    const float* x    = (const float*)d_in[0];
    const float* grid = (const float*)d_in[1];
    const float* w0   = (const float*)d_in[2];
    const float* b0   = (const float*)d_in[3];
    const float* w1   = (const float*)d_in[4];
    const float* b1   = (const float*)d_in[5];
    const float* w2   = (const float*)d_in[6];
    const float* b2   = (const float*)d_in[7];
    float* out = (float*)d_out;

    const size_t vt_bytes  = (size_t)8 * TTAB * 16;          // 8 MB supertable
    const size_t b0f_bytes = 4 * 64 * 4 * sizeof(_Float16);  // 2 KB
    const size_t b1f_bytes = 8 * 64 * 4 * sizeof(_Float16);  // 4 KB
    const size_t g8_bytes  = (size_t)8 * TTAB * 2;           // 1 MB int8 grid
    if (ws_size >= vt_bytes + b0f_bytes + b1f_bytes + g8_bytes) {
        uint4* V = (uint4*)d_ws;
        _Float16* b0f = (_Float16*)((char*)d_ws + vt_bytes);
        _Float16* b1f = (_Float16*)((char*)d_ws + vt_bytes + b0f_bytes);
        ushort* G8 = (ushort*)((char*)d_ws + vt_bytes + b0f_bytes + b1f_bytes);
        convert_i8_pack<<<256, 256, 0, stream>>>(grid, G8, w0, w1, b0f, b1f);
        build_supertable_v2<<<512, 256, 0, stream>>>(G8, V);
        ngp_mfma<<<NPTS / 256, 256, 0, stream>>>(
            x, b0, b1, w2, b2, out, V, b0f, b1f);
    } else {
        ngp_fallback<<<NPTS / 256, 256, 0, stream>>>(
            x, grid, w0, b0, w1, b1, w2, b2, out);
    }
}